// Round 3
// baseline (60.057 us; speedup 1.0000x reference)
//
#include <hip/hip_runtime.h>
#include <cmath>
#include <complex>

// ChebyUpsample: x (256, 32768) f32 -> repeat x2 -> reverse -> cheby1(8,0.05,0.5)
// 4-biquad cascade -> reverse -> y (256, 65536) f32.
// Reversed-time chunked IIR: 1024 chunks/row, 32 input samples (64 outputs) per
// thread, warm-up W=128 steps. Warm-up groups past the signal start feed 0.0,
// which is exact (zero state before signal start). Loads are software-pipelined
// (load next 8-input group while filtering current) so each load has ~512
// issue-cycles of compute to hide under.

struct SosC {
  float g;       // kz gain folded into section-0 input
  float a1[4];
  float a2[4];
};

struct G2 { float4 a, b; };   // a = x[j..j+3], b = x[j+4..j+7]

__global__ __launch_bounds__(256)
void cheby_up_kernel(const float* __restrict__ x, float* __restrict__ y, SosC c) {
  const int T_IN = 32768;
  const int row = blockIdx.y;
  const int k = blockIdx.x * 256 + threadIdx.x;   // chunk id, 0..1023
  const float* xr = x + (size_t)row * T_IN;
  float* yr = y + (size_t)row * (size_t)(2 * T_IN);

  const float g = c.g;
  const float a10 = c.a1[0], a20 = c.a2[0];
  const float a11 = c.a1[1], a21 = c.a2[1];
  const float a12 = c.a1[2], a22 = c.a2[2];
  const float a13 = c.a1[3], a23 = c.a2[3];

  // transposed direct-form II states, 4 sections
  float z10=0.f, z20=0.f, z11=0.f, z21=0.f;
  float z12=0.f, z22=0.f, z13=0.f, z23=0.f;

  // chunk owns input indices [je, je+31] -> forward outputs [2*je, 2*je+63]
  const int je = T_IN - 32 - 32 * k;

  auto step = [&](float x0) -> float {
    float y0 = x0 + z10;
    z10 = fmaf(-a10, y0, fmaf(2.f, x0, z20));
    z20 = fmaf(-a20, y0, x0);
    float y1 = y0 + z11;
    z11 = fmaf(-a11, y1, fmaf(2.f, y0, z21));
    z21 = fmaf(-a21, y1, y0);
    float y2 = y1 + z12;
    z12 = fmaf(-a12, y2, fmaf(2.f, y1, z22));
    z22 = fmaf(-a22, y2, y1);
    float y3 = y2 + z13;
    z13 = fmaf(-a13, y3, fmaf(2.f, y2, z23));
    z23 = fmaf(-a23, y3, y2);
    return y3;
  };

  // load 8 inputs starting at forward index j; indices >= T_IN read as 0.0
  // (exact: state is zero before the reversed-time signal start)
  auto ld = [&](int j) -> G2 {
    G2 r;
    const float4 z4 = make_float4(0.f, 0.f, 0.f, 0.f);
    r.a = (j     < T_IN) ? *reinterpret_cast<const float4*>(xr + j)     : z4;
    r.b = (j + 4 < T_IN) ? *reinterpret_cast<const float4*>(xr + j + 4) : z4;
    return r;
  };

  // filter 8 inputs (16 steps), reversed-time order = forward descending
  auto steps16 = [&](const G2& v) {
    float s;
    s = g * v.b.w; step(s); step(s);
    s = g * v.b.z; step(s); step(s);
    s = g * v.b.y; step(s); step(s);
    s = g * v.b.x; step(s); step(s);
    s = g * v.a.w; step(s); step(s);
    s = g * v.a.z; step(s); step(s);
    s = g * v.a.y; step(s); step(s);
    s = g * v.a.x; step(s); step(s);
  };

  // ---- warm-up: 8 groups (64 inputs = 128 steps), forward [je+32, je+96) ----
  G2 cur = ld(je + 88);                     // group wg=7 (highest forward idx)
  #pragma unroll 1
  for (int wg = 7; wg >= 1; --wg) {
    G2 nxt = ld(je + 32 + 8 * (wg - 1));
    steps16(cur);
    cur = nxt;
  }
  {                                          // last warm group; prefetch main mg=3
    G2 nxt = ld(je + 24);
    steps16(cur);
    cur = nxt;
  }

  // ---- main: 4 groups x 8 inputs -> 16 outputs (one 64B line) each ----
  // input m (forward) yields forward outputs 2m+1 then 2m.
  #pragma unroll
  for (int mg = 3; mg >= 0; --mg) {
    G2 nxt;
    if (mg > 0) nxt = ld(je + 8 * (mg - 1));
    float o0,o1,o2,o3,o4,o5,o6,o7,o8,o9,o10,o11,o12,o13,o14,o15;
    float s;
    s = g * cur.b.w; o15 = step(s); o14 = step(s);
    s = g * cur.b.z; o13 = step(s); o12 = step(s);
    s = g * cur.b.y; o11 = step(s); o10 = step(s);
    s = g * cur.b.x; o9  = step(s); o8  = step(s);
    s = g * cur.a.w; o7  = step(s); o6  = step(s);
    s = g * cur.a.z; o5  = step(s); o4  = step(s);
    s = g * cur.a.y; o3  = step(s); o2  = step(s);
    s = g * cur.a.x; o1  = step(s); o0  = step(s);
    float* yp = yr + 2 * je + 16 * mg;       // 64B-aligned (2*je mult of 64)
    *reinterpret_cast<float4*>(yp)      = make_float4(o0,  o1,  o2,  o3);
    *reinterpret_cast<float4*>(yp + 4)  = make_float4(o4,  o5,  o6,  o7);
    *reinterpret_cast<float4*>(yp + 8)  = make_float4(o8,  o9,  o10, o11);
    *reinterpret_cast<float4*>(yp + 12) = make_float4(o12, o13, o14, o15);
    if (mg > 0) cur = nxt;
  }
}

// Host-side replication of _cheby1_sos(8, 0.05, 0.5) in double precision.
static SosC compute_coefs() {
  const int N = 8;
  const double rp = 0.05, Wn = 0.5;
  const double PI = 3.14159265358979323846;
  double eps = std::sqrt(std::pow(10.0, 0.1 * rp) - 1.0);
  double mu = std::asinh(1.0 / eps) / (double)N;
  std::complex<double> p[8];
  std::complex<double> prodNegP(1.0, 0.0);
  int idx = 0;
  for (int m = -N + 1; m < N; m += 2) {
    double theta = PI * (double)m / (2.0 * N);
    std::complex<double> pp = -std::sinh(std::complex<double>(mu, theta));
    p[idx++] = pp;
    prodNegP *= -pp;
  }
  double k = prodNegP.real();
  k /= std::sqrt(1.0 + eps * eps);          // even N
  const double fs = 2.0;
  double warped = 2.0 * fs * std::tan(PI * Wn / fs);
  for (int i = 0; i < 8; i++) p[i] *= warped;
  k *= std::pow(warped, (double)N);
  const double fs2 = 2.0 * fs;
  std::complex<double> prodDen(1.0, 0.0);
  for (int i = 0; i < 8; i++) prodDen *= (fs2 - p[i]);
  double kz = k * (1.0 / prodDen).real();

  SosC c;
  int s = 0;
  for (int i = 0; i < 8; i++) {
    std::complex<double> pz = (fs2 + p[i]) / (fs2 - p[i]);
    if (pz.imag() > 0.0) {                  // same selection order as numpy
      c.a1[s] = (float)(-2.0 * pz.real());
      c.a2[s] = (float)std::norm(pz);       // |pz|^2
      s++;
    }
  }
  c.g = (float)kz;
  return c;
}

extern "C" void kernel_launch(void* const* d_in, const int* in_sizes, int n_in,
                              void* d_out, int out_size, void* d_ws, size_t ws_size,
                              hipStream_t stream) {
  const float* x = (const float*)d_in[0];
  float* y = (float*)d_out;
  SosC c = compute_coefs();
  int rows = in_sizes[0] / 32768;   // 256
  dim3 grid(4, rows);               // 1024 chunks/row, 256 threads/block
  cheby_up_kernel<<<grid, 256, 0, stream>>>(x, y, c);
}

// Round 4
// 32.652 us; speedup vs baseline: 1.8393x; 1.8393x over previous
//
#include <hip/hip_runtime.h>
#include <cmath>
#include <complex>

// ChebyUpsample: x (256, 32768) f32 -> repeat x2 -> reverse -> cheby1(8,0.05,0.5)
// 4-biquad cascade -> reverse -> y (256, 65536) f32.
// Reversed-time chunked IIR, fully LDS-staged for coalescing:
//   block = 256 threads = 256 chunks of 32 inputs (64 outputs) each.
//   Input tile (8192 + 64-halo floats) loaded coalesced -> swizzled LDS.
//   Each thread filters its chunk from LDS (warm-up 128 steps from halo;
//   zeros past signal end are exact). 64 outputs kept in registers, then
//   transposed through a 16KB LDS buffer in 4 rounds -> coalesced stores.
// LDS swizzle w = q ^ (((q>>6)&7)<<2): 16B-granular, alignment-preserving,
// bijective; spreads stride-32-float reads across all bank groups.

struct SosC {
  float g;       // kz gain folded into staged input
  float a1[4];
  float a2[4];
};

struct G2 { float4 a, b; };   // a = s[qq..qq+3], b = s[qq+4..qq+7]

#define SWZ(q) ((q) ^ ((((q) >> 6) & 7) << 2))

__global__ __launch_bounds__(256)
void cheby_up_kernel(const float* __restrict__ x, float* __restrict__ y, SosC c) {
  constexpr int T_IN = 32768;
  __shared__ __align__(16) float lin[8256];    // 8192 tile + 64 halo, swizzled
  __shared__ __align__(16) float lout[4096];   // 64-chunk output transpose buf

  const int row = blockIdx.y;
  const int b   = blockIdx.x;          // tile 0..3 within row
  const int t   = threadIdx.x;         // local chunk id 0..255
  const float* xrow = x + (size_t)row * T_IN;
  float*       yrow = y + (size_t)row * (size_t)(2 * T_IN);
  const int tbase = b * 8192;

  const float g = c.g;

  // ---- stage input tile, coalesced, pre-scaled by g ----
  #pragma unroll
  for (int j = 0; j < 8; ++j) {
    int q = 4 * t + 1024 * j;                       // 0..8191
    float4 v = *reinterpret_cast<const float4*>(xrow + tbase + q);
    v.x *= g; v.y *= g; v.z *= g; v.w *= g;
    *reinterpret_cast<float4*>(&lin[SWZ(q)]) = v;
  }
  if (t < 16) {                                     // 64-float halo
    int q = 8192 + 4 * t;
    int gi = tbase + q;
    float4 v = make_float4(0.f, 0.f, 0.f, 0.f);
    if (gi < T_IN) {
      v = *reinterpret_cast<const float4*>(xrow + gi);
      v.x *= g; v.y *= g; v.z *= g; v.w *= g;
    }
    *reinterpret_cast<float4*>(&lin[SWZ(q)]) = v;
  }
  __syncthreads();

  const float a10 = c.a1[0], a20 = c.a2[0];
  const float a11 = c.a1[1], a21 = c.a2[1];
  const float a12 = c.a1[2], a22 = c.a2[2];
  const float a13 = c.a1[3], a23 = c.a2[3];

  // transposed direct-form II states, 4 sections
  float z10=0.f, z20=0.f, z11=0.f, z21=0.f;
  float z12=0.f, z22=0.f, z13=0.f, z23=0.f;

  auto step = [&](float x0) -> float {
    float y0 = x0 + z10;
    z10 = fmaf(-a10, y0, fmaf(2.f, x0, z20));
    z20 = fmaf(-a20, y0, x0);
    float y1 = y0 + z11;
    z11 = fmaf(-a11, y1, fmaf(2.f, y0, z21));
    z21 = fmaf(-a21, y1, y0);
    float y2 = y1 + z12;
    z12 = fmaf(-a12, y2, fmaf(2.f, y1, z22));
    z22 = fmaf(-a22, y2, y1);
    float y3 = y2 + z13;
    z13 = fmaf(-a13, y3, fmaf(2.f, y2, z23));
    z23 = fmaf(-a23, y3, y2);
    return y3;
  };

  auto rd8 = [&](int qq) -> G2 {     // 8 consecutive staged samples
    G2 r;
    r.a = *reinterpret_cast<const float4*>(&lin[SWZ(qq)]);
    r.b = *reinterpret_cast<const float4*>(&lin[SWZ(qq + 4)]);
    return r;
  };

  // 16 filter steps over 8 inputs, reversed-time order = forward descending
  auto steps16 = [&](const G2& v) {
    float s;
    s = v.b.w; step(s); step(s);
    s = v.b.z; step(s); step(s);
    s = v.b.y; step(s); step(s);
    s = v.b.x; step(s); step(s);
    s = v.a.w; step(s); step(s);
    s = v.a.z; step(s); step(s);
    s = v.a.y; step(s); step(s);
    s = v.a.x; step(s); step(s);
  };

  float o[64];   // chunk outputs, local forward offsets 0..63 (all static idx)

  // ---- warm-up: 8 groups (64 inputs = 128 steps), chunk offsets [32,96) ----
  G2 cur = rd8(32 * t + 88);
  #pragma unroll
  for (int wg = 7; wg >= 1; --wg) {
    G2 nxt = rd8(32 * t + 32 + 8 * (wg - 1));
    steps16(cur);
    cur = nxt;
  }
  {
    G2 nxt = rd8(32 * t + 24);      // prefetch main mg=3
    steps16(cur);
    cur = nxt;
  }

  // ---- main: 4 groups x 8 inputs -> 16 outputs each (forward descending) ----
  #pragma unroll
  for (int mg = 3; mg >= 0; --mg) {
    G2 nxt = cur;
    if (mg > 0) nxt = rd8(32 * t + 8 * (mg - 1));
    float s;
    s = cur.b.w; o[16*mg+15] = step(s); o[16*mg+14] = step(s);
    s = cur.b.z; o[16*mg+13] = step(s); o[16*mg+12] = step(s);
    s = cur.b.y; o[16*mg+11] = step(s); o[16*mg+10] = step(s);
    s = cur.b.x; o[16*mg+9]  = step(s); o[16*mg+8]  = step(s);
    s = cur.a.w; o[16*mg+7]  = step(s); o[16*mg+6]  = step(s);
    s = cur.a.z; o[16*mg+5]  = step(s); o[16*mg+4]  = step(s);
    s = cur.a.y; o[16*mg+3]  = step(s); o[16*mg+2]  = step(s);
    s = cur.a.x; o[16*mg+1]  = step(s); o[16*mg+0]  = step(s);
    cur = nxt;
  }

  // ---- flush: 4 rounds x 64 chunks through 16KB transpose buffer ----
  #pragma unroll 1
  for (int r = 0; r < 4; ++r) {
    __syncthreads();                  // prev round's reads done / compute done
    int cp = t - 64 * r;              // writer wave: threads [64r, 64r+64)
    if (cp >= 0 && cp < 64) {
      #pragma unroll
      for (int j = 0; j < 16; ++j) {
        int q = 64 * cp + 4 * j;
        *reinterpret_cast<float4*>(&lout[SWZ(q)]) =
            make_float4(o[4*j], o[4*j+1], o[4*j+2], o[4*j+3]);
      }
    }
    __syncthreads();
    #pragma unroll
    for (int j = 0; j < 4; ++j) {     // coalesced store of 16KB
      int q = 4 * t + 1024 * j;
      float4 v = *reinterpret_cast<const float4*>(&lout[SWZ(q)]);
      *reinterpret_cast<float4*>(yrow + 16384 * b + 4096 * r + q) = v;
    }
  }
}

// Host-side replication of _cheby1_sos(8, 0.05, 0.5) in double precision.
static SosC compute_coefs() {
  const int N = 8;
  const double rp = 0.05, Wn = 0.5;
  const double PI = 3.14159265358979323846;
  double eps = std::sqrt(std::pow(10.0, 0.1 * rp) - 1.0);
  double mu = std::asinh(1.0 / eps) / (double)N;
  std::complex<double> p[8];
  std::complex<double> prodNegP(1.0, 0.0);
  int idx = 0;
  for (int m = -N + 1; m < N; m += 2) {
    double theta = PI * (double)m / (2.0 * N);
    std::complex<double> pp = -std::sinh(std::complex<double>(mu, theta));
    p[idx++] = pp;
    prodNegP *= -pp;
  }
  double k = prodNegP.real();
  k /= std::sqrt(1.0 + eps * eps);          // even N
  const double fs = 2.0;
  double warped = 2.0 * fs * std::tan(PI * Wn / fs);
  for (int i = 0; i < 8; i++) p[i] *= warped;
  k *= std::pow(warped, (double)N);
  const double fs2 = 2.0 * fs;
  std::complex<double> prodDen(1.0, 0.0);
  for (int i = 0; i < 8; i++) prodDen *= (fs2 - p[i]);
  double kz = k * (1.0 / prodDen).real();

  SosC c;
  int s = 0;
  for (int i = 0; i < 8; i++) {
    std::complex<double> pz = (fs2 + p[i]) / (fs2 - p[i]);
    if (pz.imag() > 0.0) {                  // same selection order as numpy
      c.a1[s] = (float)(-2.0 * pz.real());
      c.a2[s] = (float)std::norm(pz);       // |pz|^2
      s++;
    }
  }
  c.g = (float)kz;
  return c;
}

extern "C" void kernel_launch(void* const* d_in, const int* in_sizes, int n_in,
                              void* d_out, int out_size, void* d_ws, size_t ws_size,
                              hipStream_t stream) {
  const float* x = (const float*)d_in[0];
  float* y = (float*)d_out;
  SosC c = compute_coefs();
  int rows = in_sizes[0] / 32768;   // 256
  dim3 grid(4, rows);               // 4 tiles/row, 256 chunks per tile
  cheby_up_kernel<<<grid, 256, 0, stream>>>(x, y, c);
}